// Round 6
// baseline (127.510 us; speedup 1.0000x reference)
//
#include <hip/hip_runtime.h>
#include <math.h>

// Problem constants
#define NT 320
#define NS 16
#define PIN 8
#define MOUT 8
// step = TMAX/(NT-1)
#define STEPF (1.0f/319.0f)

// ---------------------------------------------------------------------------
// Wave-level 16x16 matmul, no barriers / no LDS.
// Layout: lane l (0..63) holds M[row][4*jb+m], row = l>>2, jb = l&3, m = 0..3
// C = A x B :  C[i][4jb+m] = sum_k A[i][k] * B[k][4jb+m]
//   A[i][k]      lives in lane (l&60)|(k>>2), reg k&3   (broadcast over jb)
//   B[k][4jb+m]  lives in lane (k<<2)|jb,     reg m
// 80 shfl + 64 fma per matmul, fully unrolled (reg index is compile-time).
// ---------------------------------------------------------------------------
__device__ __forceinline__ float4 wave_mm(const float4 A, const float4 B,
                                          const int lane) {
    float4 c = make_float4(0.f, 0.f, 0.f, 0.f);
    const int rowbase = lane & 60;
    const int jb = lane & 3;
#pragma unroll
    for (int k = 0; k < 16; ++k) {
        const int srcA = rowbase | (k >> 2);
        float a;
        if ((k & 3) == 0)      a = __shfl(A.x, srcA);
        else if ((k & 3) == 1) a = __shfl(A.y, srcA);
        else if ((k & 3) == 2) a = __shfl(A.z, srcA);
        else                   a = __shfl(A.w, srcA);
        const int srcB = (k << 2) | jb;
        c.x += a * __shfl(B.x, srcB);
        c.y += a * __shfl(B.y, srcB);
        c.z += a * __shfl(B.z, srcB);
        c.w += a * __shfl(B.w, srcB);
    }
    return c;
}

// ---------------------------------------------------------------------------
// Phase 1: 80 blocks x 256 thr.  Block builds A (16x16) once in LDS
// (barriered, amortized over 4 time indices, 80 concurrent blocks), then
// each wave computes E_k = expm(A * t_k) for its own k = bx*4 + wave via
// scaling-squaring + Taylor-9 Horner (theta=0.5, rem ~3e-10) using
// barrier-free shuffle matmuls.  Epilogue (2 barriers): CE_k = C E_k,
// Mrow_k = CE_k cov0, G_k = CE_k B, y1_k = CE_k x0.
// ---------------------------------------------------------------------------
__global__ void k_phase1(const float* __restrict__ V1r,
                         const float* __restrict__ V2r,
                         const float* __restrict__ V3r,
                         const float* __restrict__ C_w,
                         const float* __restrict__ B_w,
                         const float* __restrict__ cov0,
                         const float* __restrict__ x0,
                         float* __restrict__ CE_g,
                         float* __restrict__ Mrow_g,
                         float* __restrict__ G_g,
                         float* __restrict__ y1_g) {
    __shared__ float M[16][16];      // V1-lower, then A
    __shared__ float Minv[16][16];
    __shared__ float Pinv[16][16];
    __shared__ float W[16][16];
    __shared__ float V2s[16][16];
    __shared__ float cov[16][16];
    __shared__ float Cs[8][16];
    __shared__ float Bw[16][8];
    __shared__ float x0s[16];
    __shared__ float rowsum[16];
    __shared__ float normA_s;
    __shared__ float Ew[4][16][16];  // per-wave E_k
    __shared__ float CEw[4][8][16];  // per-wave CE_k
    const int tid = threadIdx.x;
    const int i = tid >> 4, j = tid & 15;

    // stage small operands
    cov[i][j] = cov0[tid];
    if (tid < 128) Cs[tid >> 4][tid & 15] = C_w[tid];
    if (tid < 128) Bw[tid >> 3][tid & 7]  = B_w[tid];
    if (tid < 16)  x0s[tid] = x0[tid];

    // --- build A (once per block) ---
    float v;
    if (i > j)       v = V1r[i * 16 + j];
    else if (i == j) v = fabsf(V1r[i * 16 + i]) + 2.0f * 1e-3f;  // eps applied twice
    else             v = 0.0f;
    M[i][j]   = v;
    V2s[i][j] = (j <= i) ? V2r[i * 16 + j] : 0.0f;
    __syncthreads();

    if (tid < 16) {  // forward substitution, column tid (V1 lower-triangular)
        const int c = tid;
        float x[16];
        for (int r = 0; r < 16; ++r) {
            if (r < c) { x[r] = 0.0f; continue; }
            float s = (r == c) ? 1.0f : 0.0f;
            for (int kk = c; kk < r; ++kk) s -= M[r][kk] * x[kk];
            x[r] = s / M[r][r];
        }
        for (int r = 0; r < 16; ++r) Minv[r][c] = x[r];
    }
    __syncthreads();

    {   // P_inv = Minv^T Minv
        float acc = 0.0f;
#pragma unroll
        for (int kk = 0; kk < 16; ++kk) acc += Minv[kk][i] * Minv[kk][j];
        Pinv[i][j] = acc;
    }
    {   // W = -0.5 V2 V2^T + V3 (V3 = triu(V3r,1) - triu^T)
        float acc = 0.0f;
#pragma unroll
        for (int kk = 0; kk < 16; ++kk) acc += V2s[i][kk] * V2s[j][kk];
        float v3 = 0.0f;
        if (j > i)      v3 =  V3r[i * 16 + j];
        else if (i > j) v3 = -V3r[j * 16 + i];
        W[i][j] = -0.5f * acc + v3;
    }
    __syncthreads();
    {   // A = P_inv @ W -> store into M (dead after substitution)
        float acc = 0.0f;
#pragma unroll
        for (int kk = 0; kk < 16; ++kk) acc += Pinv[i][kk] * W[kk][j];
        M[i][j] = acc;
    }
    __syncthreads();
    if (j == 0) {
        float r = 0.0f;
#pragma unroll
        for (int kk = 0; kk < 16; ++kk) r += fabsf(M[i][kk]);
        rowsum[i] = r;
    }
    __syncthreads();
    if (tid == 0) {
        float m = 0.0f;
        for (int kk = 0; kk < 16; ++kk) m = fmaxf(m, rowsum[kk]);
        normA_s = m;
    }
    __syncthreads();

    // --- per-wave expm, barrier-free shuffle matmuls ---
    const int wave = tid >> 6;
    const int lane = tid & 63;
    const int k    = blockIdx.x * 4 + wave;   // 80*4 = 320 exactly
    const float t  = (float)k * STEPF;
    const int row  = lane >> 2, jb = lane & 3;

    // identity fragment for this lane
    float4 idf;
    idf.x = (row == 4 * jb + 0) ? 1.0f : 0.0f;
    idf.y = (row == 4 * jb + 1) ? 1.0f : 0.0f;
    idf.z = (row == 4 * jb + 2) ? 1.0f : 0.0f;
    idf.w = (row == 4 * jb + 3) ? 1.0f : 0.0f;

    // load A fragment (16B per lane)
    float4 Af = *((const float4*)&M[row][jb * 4]);

    // scaling so ||A t / 2^s||_inf <= 0.5
    float nt = normA_s * t;
    int s = 0;
    while (nt > 0.5f && s < 30) { nt *= 0.5f; ++s; }
    const float scale = t * exp2f((float)(-s));
    float4 Bh;
    Bh.x = Af.x * scale; Bh.y = Af.y * scale;
    Bh.z = Af.z * scale; Bh.w = Af.w * scale;

    // Horner: P = I + Bh/9 ; then P = I + (Bh P)/d for d = 8..1
    float4 P;
    P.x = idf.x + Bh.x * (1.0f / 9.0f);
    P.y = idf.y + Bh.y * (1.0f / 9.0f);
    P.z = idf.z + Bh.z * (1.0f / 9.0f);
    P.w = idf.w + Bh.w * (1.0f / 9.0f);
#pragma unroll
    for (int d = 8; d >= 1; --d) {
        const float4 c = wave_mm(Bh, P, lane);
        const float inv = 1.0f / (float)d;
        P.x = idf.x + c.x * inv;
        P.y = idf.y + c.y * inv;
        P.z = idf.z + c.z * inv;
        P.w = idf.w + c.w * inv;
    }
    // squarings
    for (int q = 0; q < s; ++q) P = wave_mm(P, P, lane);

    // park E_k in this wave's LDS slab
    *((float4*)&Ew[wave][row][jb * 4]) = P;
    __syncthreads();

    // CE = C @ E (8x16): 2 elements per lane (same row, adjacent cols)
    {
        const int idx = lane * 2;
        const int a8 = idx >> 4, c0 = idx & 15;
        float acc0 = 0.0f, acc1 = 0.0f;
#pragma unroll
        for (int kk = 0; kk < 16; ++kk) {
            const float cw = Cs[a8][kk];
            acc0 += cw * Ew[wave][kk][c0];
            acc1 += cw * Ew[wave][kk][c0 + 1];
        }
        CEw[wave][a8][c0]     = acc0;
        CEw[wave][a8][c0 + 1] = acc1;
        CE_g[k * 128 + idx]     = acc0;
        CE_g[k * 128 + idx + 1] = acc1;
    }
    __syncthreads();

    // Mrow = CE @ cov0 (8x16): 2 elements per lane
    {
        const int idx = lane * 2;
        const int a8 = idx >> 4, l0 = idx & 15;
        float acc0 = 0.0f, acc1 = 0.0f;
#pragma unroll
        for (int kk = 0; kk < 16; ++kk) {
            const float ce = CEw[wave][a8][kk];
            acc0 += ce * cov[kk][l0];
            acc1 += ce * cov[kk][l0 + 1];
        }
        Mrow_g[k * 128 + idx]     = acc0;
        Mrow_g[k * 128 + idx + 1] = acc1;
    }
    // G = CE @ B_w (8x8): 1 element per lane
    {
        const int a8 = lane >> 3, p = lane & 7;
        float acc = 0.0f;
#pragma unroll
        for (int kk = 0; kk < 16; ++kk) acc += CEw[wave][a8][kk] * Bw[kk][p];
        G_g[k * 64 + lane] = acc;
    }
    // y1 = CE @ x0 (8)
    if (lane < 8) {
        float acc = 0.0f;
#pragma unroll
        for (int kk = 0; kk < 16; ++kk) acc += CEw[wave][lane][kk] * x0s[kk];
        y1_g[k * 8 + lane] = acc;
    }
}

// ---------------------------------------------------------------------------
// Phase 2 (fused covar + mean): grid (21, 320) x 256 thr.
//  bx in [0,20): covar1 tile (16 j's) + covar_U slice for row i.
//  bx == 20:     mean_y row i (trapezoid conv, LDS tree-reduce).
// ---------------------------------------------------------------------------
__global__ void k_phase2(const float* __restrict__ Mrow_g,
                         const float* __restrict__ CE_g,
                         const float* __restrict__ y1_g,
                         const float* __restrict__ G_g,
                         const float* __restrict__ U,
                         const float* __restrict__ dU,
                         const float* __restrict__ D_w,
                         float* __restrict__ out_c1,
                         float* __restrict__ out_cu,
                         float* __restrict__ out_mean) {
    const int bx  = blockIdx.x;   // 0..20
    const int i   = blockIdx.y;   // 0..319
    const int tid = threadIdx.x;

    if (bx < 20) {
        __shared__ float Mi[128];
        __shared__ float CEj[2048];
        const int jg = bx;
        {   // vectorized staging: CEj = 512 float4, Mi = 32 float4
            const float4* srcC = (const float4*)(CE_g + jg * 2048);
            float4* dstC = (float4*)CEj;
            dstC[tid]       = srcC[tid];
            dstC[tid + 256] = srcC[tid + 256];
            if (tid < 32) ((float4*)Mi)[tid] = ((const float4*)(Mrow_g + i * 128))[tid];
        }
        __syncthreads();

        const int jj = tid >> 4;         // 0..15
        const int a  = (tid >> 1) & 7;   // 0..7
        const int bg = tid & 1;          // 0..1 (4 b's each)
        const float* mi = Mi + a * 16;
        const float* ce = CEj + jj * 128 + bg * 64;
        float r[4];
#pragma unroll
        for (int b = 0; b < 4; ++b) {
            float acc = 0.0f;
#pragma unroll
            for (int l = 0; l < 16; ++l) acc += mi[l] * ce[b * 16 + l];
            r[b] = acc;
        }
        const int j = jg * 16 + jj;
        float4* dst = (float4*)(out_c1 + ((size_t)(i * 320 + j)) * 64 + a * 8 + bg * 4);
        *dst = make_float4(r[0], r[1], r[2], r[3]);

        if (tid < 16) {
            const int jx = jg * 16 + tid;
            const float d = (float)(i - jx) * STEPF;
            out_cu[i * 320 + jx] = expf(-50.0f * d * d);  // LT=0.1 -> 1/(2 LT^2)=50
        }
    } else {
        __shared__ float part[256];
        const int m  = tid & 7;
        const int js = tid >> 3;          // 0..31
        float acc = 0.0f;
        if (i > 0) {
            for (int j = js; j <= i; j += 32) {
                const float w = ((j == 0) || (j == i)) ? 0.5f : 1.0f;
                const float4* Gr = (const float4*)(G_g + (i - j) * 64 + m * 8);
                const float4* Ur = (const float4*)(U + j * 8);
                const float4 g0 = Gr[0], g1 = Gr[1];
                const float4 u0 = Ur[0], u1 = Ur[1];
                float d = g0.x * u0.x + g0.y * u0.y + g0.z * u0.z + g0.w * u0.w
                        + g1.x * u1.x + g1.y * u1.y + g1.z * u1.z + g1.w * u1.w;
                acc += w * d;
            }
        }
        part[tid] = acc;
        __syncthreads();
#pragma unroll
        for (int off = 128; off >= 8; off >>= 1) {
            if (tid < off) part[tid] += part[tid + off];
            __syncthreads();
        }
        if (tid < 8) {
            float t3 = 0.0f;
#pragma unroll
            for (int p = 0; p < 8; ++p) t3 += D_w[tid * 8 + p] * dU[i * 8 + p];
            out_mean[i * 8 + tid] = y1_g[i * 8 + tid] + STEPF * part[tid] + t3;
        }
    }
}

// ---------------------------------------------------------------------------
extern "C" void kernel_launch(void* const* d_in, const int* in_sizes, int n_in,
                              void* d_out, int out_size, void* d_ws, size_t ws_size,
                              hipStream_t stream) {
    const float* V1r  = (const float*)d_in[0];
    const float* V2r  = (const float*)d_in[1];
    const float* V3r  = (const float*)d_in[2];
    const float* B_w  = (const float*)d_in[3];
    const float* C_w  = (const float*)d_in[4];
    const float* D_w  = (const float*)d_in[5];
    const float* x0   = (const float*)d_in[6];
    const float* cov0 = (const float*)d_in[7];
    const float* U    = (const float*)d_in[8];
    const float* dU   = (const float*)d_in[9];

    float* ws   = (float*)d_ws;
    float* CE   = ws;             // 320*128 = 40960
    float* Mrow = CE + 40960;     // 40960
    float* G    = Mrow + 40960;   // 320*64 = 20480
    float* y1   = G + 20480;      // 2560

    float* out      = (float*)d_out;
    float* out_mean = out;                      // 320*8
    float* out_c1   = out + 2560;               // 320*320*64
    float* out_cu   = out + 2560 + 320*320*64;  // 320*320

    k_phase1<<<80, 256, 0, stream>>>(V1r, V2r, V3r, C_w, B_w, cov0, x0,
                                     CE, Mrow, G, y1);
    k_phase2<<<dim3(21, NT), 256, 0, stream>>>(Mrow, CE, y1, G, U, dU, D_w,
                                               out_c1, out_cu, out_mean);
}

// Round 7
// 107.033 us; speedup vs baseline: 1.1913x; 1.1913x over previous
//
#include <hip/hip_runtime.h>
#include <math.h>

// Problem constants
#define NT 320
#define NS 16
#define PIN 8
#define MOUT 8
// step = TMAX/(NT-1)
#define STEPF (1.0f/319.0f)

// ---------------------------------------------------------------------------
// Wave-level 16x16 matmuls, fragment layout: lane l holds M[row][4*jb+m],
// row = l>>2, jb = l&3, m = 0..3 (one float4 per lane).
// ---------------------------------------------------------------------------

// C = A x B : C[i][4jb+m] = sum_k A[i][k]*B[k][4jb+m]
__device__ __forceinline__ float4 wave_mm(const float4 A, const float4 B,
                                          const int lane) {
    float4 c = make_float4(0.f, 0.f, 0.f, 0.f);
    const int rowbase = lane & 60;
    const int jb = lane & 3;
#pragma unroll
    for (int k = 0; k < 16; ++k) {
        const int srcA = rowbase | (k >> 2);
        float a;
        if ((k & 3) == 0)      a = __shfl(A.x, srcA);
        else if ((k & 3) == 1) a = __shfl(A.y, srcA);
        else if ((k & 3) == 2) a = __shfl(A.z, srcA);
        else                   a = __shfl(A.w, srcA);
        const int srcB = (k << 2) | jb;
        c.x += a * __shfl(B.x, srcB);
        c.y += a * __shfl(B.y, srcB);
        c.z += a * __shfl(B.z, srcB);
        c.w += a * __shfl(B.w, srcB);
    }
    return c;
}

// C = A x B^T : C[i][4jb+m] = sum_k A[i][k]*B[4jb+m][k]
__device__ __forceinline__ float4 wave_mm_abt(const float4 A, const float4 B,
                                              const int lane) {
    float4 c = make_float4(0.f, 0.f, 0.f, 0.f);
    const int rowbase = lane & 60;
    const int jb = lane & 3;
#pragma unroll
    for (int k = 0; k < 16; ++k) {
        const int hk = k >> 2;
        float a, b0, b1, b2, b3;
        if ((k & 3) == 0) {
            a  = __shfl(A.x, rowbase | hk);
            b0 = __shfl(B.x, (jb << 4) | 0 | hk);
            b1 = __shfl(B.x, (jb << 4) | 4 | hk);
            b2 = __shfl(B.x, (jb << 4) | 8 | hk);
            b3 = __shfl(B.x, (jb << 4) | 12 | hk);
        } else if ((k & 3) == 1) {
            a  = __shfl(A.y, rowbase | hk);
            b0 = __shfl(B.y, (jb << 4) | 0 | hk);
            b1 = __shfl(B.y, (jb << 4) | 4 | hk);
            b2 = __shfl(B.y, (jb << 4) | 8 | hk);
            b3 = __shfl(B.y, (jb << 4) | 12 | hk);
        } else if ((k & 3) == 2) {
            a  = __shfl(A.z, rowbase | hk);
            b0 = __shfl(B.z, (jb << 4) | 0 | hk);
            b1 = __shfl(B.z, (jb << 4) | 4 | hk);
            b2 = __shfl(B.z, (jb << 4) | 8 | hk);
            b3 = __shfl(B.z, (jb << 4) | 12 | hk);
        } else {
            a  = __shfl(A.w, rowbase | hk);
            b0 = __shfl(B.w, (jb << 4) | 0 | hk);
            b1 = __shfl(B.w, (jb << 4) | 4 | hk);
            b2 = __shfl(B.w, (jb << 4) | 8 | hk);
            b3 = __shfl(B.w, (jb << 4) | 12 | hk);
        }
        c.x += a * b0; c.y += a * b1; c.z += a * b2; c.w += a * b3;
    }
    return c;
}

// ---------------------------------------------------------------------------
// Phase 1: 320 blocks x 64 threads — ONE WAVE per time index k.  Zero
// cross-wave synchronization.  Build A in-wave (LDS only for the triangular
// substitution; __syncthreads on a 1-wave block is a near-free waitcnt),
// then expm(A*t_k) = scaling-squaring + Taylor-9 Horner via shuffle matmuls,
// epilogue (CE/Mrow/G/y1) via shuffle matmuls on padded 16x16 forms.
// ---------------------------------------------------------------------------
__global__ __launch_bounds__(64) void k_phase1(
        const float* __restrict__ V1r,
        const float* __restrict__ V2r,
        const float* __restrict__ V3r,
        const float* __restrict__ C_w,
        const float* __restrict__ B_w,
        const float* __restrict__ cov0,
        const float* __restrict__ x0,
        float* __restrict__ CE_g,
        float* __restrict__ Mrow_g,
        float* __restrict__ G_g,
        float* __restrict__ y1_g) {
    __shared__ float Msub[16][16];
    __shared__ float MinvT[16][16];
    __shared__ float V3s[16][16];
    const int lane = threadIdx.x;
    const int row = lane >> 2, jb = lane & 3;
    const int k = blockIdx.x;
    const float t = (float)k * STEPF;

    // --- load fragments ---
    const float4 v1 = *((const float4*)(V1r + row * 16 + jb * 4));
    const float4 v2 = *((const float4*)(V2r + row * 16 + jb * 4));
    const float4 v3raw = *((const float4*)(V3r + row * 16 + jb * 4));

    // M = tril(V1,-1) + |diag|+2eps ;  V2f = tril(V2)
    float4 Mf, V2f;
    {
        const float mv[4] = {v1.x, v1.y, v1.z, v1.w};
        const float vv[4] = {v2.x, v2.y, v2.z, v2.w};
        float mo[4], vo[4];
#pragma unroll
        for (int m = 0; m < 4; ++m) {
            const int col = jb * 4 + m;
            mo[m] = (row > col) ? mv[m]
                  : ((row == col) ? (fabsf(mv[m]) + 2.0f * 1e-3f) : 0.0f);
            vo[m] = (col <= row) ? vv[m] : 0.0f;
        }
        Mf  = make_float4(mo[0], mo[1], mo[2], mo[3]);
        V2f = make_float4(vo[0], vo[1], vo[2], vo[3]);
    }
    *((float4*)&Msub[row][jb * 4]) = Mf;
    *((float4*)&V3s[row][jb * 4])  = v3raw;
    __syncthreads();  // 1-wave block: compiles to a cheap waitcnt+barrier

    // --- forward substitution: column c = lane (V1 lower-triangular) ---
    if (lane < 16) {
        const int c = lane;
        float x[16];
#pragma unroll
        for (int r = 0; r < 16; ++r) {
            float s = (r == c) ? 1.0f : 0.0f;
#pragma unroll
            for (int kk = 0; kk < 16; ++kk) {
                if (kk < r) s -= Msub[r][kk] * x[kk];
            }
            x[r] = (r < c) ? 0.0f : s / Msub[r][r];
        }
#pragma unroll
        for (int r = 0; r < 16; ++r) MinvT[c][r] = x[r];
    }
    __syncthreads();

    // V3 fragment: V3[i][j] = (j>i)? V3r[i][j] : (i>j ? -V3r[j][i] : 0)
    float4 V3f;
    {
        float o[4];
#pragma unroll
        for (int m = 0; m < 4; ++m) {
            const int col = jb * 4 + m;
            const float up = V3s[row][col];
            const float lo = V3s[col][row];
            o[m] = (col > row) ? up : ((row > col) ? -lo : 0.0f);
        }
        V3f = make_float4(o[0], o[1], o[2], o[3]);
    }
    const float4 Tf = *((const float4*)&MinvT[row][jb * 4]);

    // Pinv = Minv^T Minv = T T^T ;  W = -0.5 V2 V2^T + V3 ;  A = Pinv W
    const float4 Pinvf = wave_mm_abt(Tf, Tf, lane);
    float4 Wf = wave_mm_abt(V2f, V2f, lane);
    Wf.x = -0.5f * Wf.x + V3f.x;
    Wf.y = -0.5f * Wf.y + V3f.y;
    Wf.z = -0.5f * Wf.z + V3f.z;
    Wf.w = -0.5f * Wf.w + V3f.w;
    const float4 Af = wave_mm(Pinvf, Wf, lane);

    // ||A||_inf via shuffle butterflies
    float s0 = fabsf(Af.x) + fabsf(Af.y) + fabsf(Af.z) + fabsf(Af.w);
    s0 += __shfl_xor(s0, 1);
    s0 += __shfl_xor(s0, 2);          // row sum in all 4 lanes of the row
    float nrm = s0;
    nrm = fmaxf(nrm, __shfl_xor(nrm, 4));
    nrm = fmaxf(nrm, __shfl_xor(nrm, 8));
    nrm = fmaxf(nrm, __shfl_xor(nrm, 16));
    nrm = fmaxf(nrm, __shfl_xor(nrm, 32));

    // scaling so ||A t / 2^s||_inf <= 0.5
    float nt = nrm * t;
    int s = 0;
    while (nt > 0.5f && s < 30) { nt *= 0.5f; ++s; }
    const float scale = t * exp2f((float)(-s));
    float4 Bh;
    Bh.x = Af.x * scale; Bh.y = Af.y * scale;
    Bh.z = Af.z * scale; Bh.w = Af.w * scale;

    // identity fragment
    float4 idf;
    idf.x = (row == 4 * jb + 0) ? 1.0f : 0.0f;
    idf.y = (row == 4 * jb + 1) ? 1.0f : 0.0f;
    idf.z = (row == 4 * jb + 2) ? 1.0f : 0.0f;
    idf.w = (row == 4 * jb + 3) ? 1.0f : 0.0f;

    // Horner: P = I + Bh/9 ; then P = I + (Bh P)/d for d = 8..1
    float4 P;
    P.x = idf.x + Bh.x * (1.0f / 9.0f);
    P.y = idf.y + Bh.y * (1.0f / 9.0f);
    P.z = idf.z + Bh.z * (1.0f / 9.0f);
    P.w = idf.w + Bh.w * (1.0f / 9.0f);
#pragma unroll
    for (int d = 8; d >= 1; --d) {
        const float4 c = wave_mm(Bh, P, lane);
        const float inv = 1.0f / (float)d;
        P.x = idf.x + c.x * inv;
        P.y = idf.y + c.y * inv;
        P.z = idf.z + c.z * inv;
        P.w = idf.w + c.w * inv;
    }
    for (int q = 0; q < s; ++q) P = wave_mm(P, P, lane);   // squarings

    // --- epilogue: CE = C@E (C padded to 16x16 by duplicating rows) ---
    const int crow = row & 7;
    const float4 Cf  = *((const float4*)(C_w + crow * 16 + jb * 4));
    const float4 CEf = wave_mm(Cf, P, lane);               // rows 0..7 valid
    const float4 covf = *((const float4*)(cov0 + row * 16 + jb * 4));
    const float4 Mrowf = wave_mm(CEf, covf, lane);         // rows 0..7 valid
    float4 Bwf = make_float4(0.f, 0.f, 0.f, 0.f);
    if (jb < 2) Bwf = *((const float4*)(B_w + row * 8 + jb * 4));
    const float4 Gf = wave_mm(CEf, Bwf, lane);             // rows<8, jb<2 valid
    const float4 x0f = *((const float4*)(x0 + jb * 4));
    float yp = CEf.x * x0f.x + CEf.y * x0f.y + CEf.z * x0f.z + CEf.w * x0f.w;
    yp += __shfl_xor(yp, 1);
    yp += __shfl_xor(yp, 2);                               // full dot in row lanes

    if (row < 8) {
        *((float4*)(CE_g   + k * 128 + row * 16 + jb * 4)) = CEf;
        *((float4*)(Mrow_g + k * 128 + row * 16 + jb * 4)) = Mrowf;
        if (jb < 2) *((float4*)(G_g + k * 64 + row * 8 + jb * 4)) = Gf;
        if (jb == 0) y1_g[k * 8 + row] = yp;
    }
}

// ---------------------------------------------------------------------------
// Phase 2 (fused covar + mean): grid (21, 320) x 256 thr.
//  bx in [0,20): covar1 tile (16 j's) + covar_U slice for row i.
//  bx == 20:     mean_y row i (trapezoid conv, LDS tree-reduce).
// ---------------------------------------------------------------------------
__global__ void k_phase2(const float* __restrict__ Mrow_g,
                         const float* __restrict__ CE_g,
                         const float* __restrict__ y1_g,
                         const float* __restrict__ G_g,
                         const float* __restrict__ U,
                         const float* __restrict__ dU,
                         const float* __restrict__ D_w,
                         float* __restrict__ out_c1,
                         float* __restrict__ out_cu,
                         float* __restrict__ out_mean) {
    const int bx  = blockIdx.x;   // 0..20
    const int i   = blockIdx.y;   // 0..319
    const int tid = threadIdx.x;

    if (bx < 20) {
        __shared__ float Mi[128];
        __shared__ float CEj[2048];
        const int jg = bx;
        {   // vectorized staging: CEj = 512 float4, Mi = 32 float4
            const float4* srcC = (const float4*)(CE_g + jg * 2048);
            float4* dstC = (float4*)CEj;
            dstC[tid]       = srcC[tid];
            dstC[tid + 256] = srcC[tid + 256];
            if (tid < 32) ((float4*)Mi)[tid] = ((const float4*)(Mrow_g + i * 128))[tid];
        }
        __syncthreads();

        const int jj = tid >> 4;         // 0..15
        const int a  = (tid >> 1) & 7;   // 0..7
        const int bg = tid & 1;          // 0..1 (4 b's each)
        const float* mi = Mi + a * 16;
        const float* ce = CEj + jj * 128 + bg * 64;
        float r[4];
#pragma unroll
        for (int b = 0; b < 4; ++b) {
            float acc = 0.0f;
#pragma unroll
            for (int l = 0; l < 16; ++l) acc += mi[l] * ce[b * 16 + l];
            r[b] = acc;
        }
        const int j = jg * 16 + jj;
        float4* dst = (float4*)(out_c1 + ((size_t)(i * 320 + j)) * 64 + a * 8 + bg * 4);
        *dst = make_float4(r[0], r[1], r[2], r[3]);

        if (tid < 16) {
            const int jx = jg * 16 + tid;
            const float d = (float)(i - jx) * STEPF;
            out_cu[i * 320 + jx] = expf(-50.0f * d * d);  // LT=0.1 -> 1/(2 LT^2)=50
        }
    } else {
        __shared__ float part[256];
        const int m  = tid & 7;
        const int js = tid >> 3;          // 0..31
        float acc = 0.0f;
        if (i > 0) {
            for (int j = js; j <= i; j += 32) {
                const float w = ((j == 0) || (j == i)) ? 0.5f : 1.0f;
                const float4* Gr = (const float4*)(G_g + (i - j) * 64 + m * 8);
                const float4* Ur = (const float4*)(U + j * 8);
                const float4 g0 = Gr[0], g1 = Gr[1];
                const float4 u0 = Ur[0], u1 = Ur[1];
                float d = g0.x * u0.x + g0.y * u0.y + g0.z * u0.z + g0.w * u0.w
                        + g1.x * u1.x + g1.y * u1.y + g1.z * u1.z + g1.w * u1.w;
                acc += w * d;
            }
        }
        part[tid] = acc;
        __syncthreads();
#pragma unroll
        for (int off = 128; off >= 8; off >>= 1) {
            if (tid < off) part[tid] += part[tid + off];
            __syncthreads();
        }
        if (tid < 8) {
            float t3 = 0.0f;
#pragma unroll
            for (int p = 0; p < 8; ++p) t3 += D_w[tid * 8 + p] * dU[i * 8 + p];
            out_mean[i * 8 + tid] = y1_g[i * 8 + tid] + STEPF * part[tid] + t3;
        }
    }
}

// ---------------------------------------------------------------------------
extern "C" void kernel_launch(void* const* d_in, const int* in_sizes, int n_in,
                              void* d_out, int out_size, void* d_ws, size_t ws_size,
                              hipStream_t stream) {
    const float* V1r  = (const float*)d_in[0];
    const float* V2r  = (const float*)d_in[1];
    const float* V3r  = (const float*)d_in[2];
    const float* B_w  = (const float*)d_in[3];
    const float* C_w  = (const float*)d_in[4];
    const float* D_w  = (const float*)d_in[5];
    const float* x0   = (const float*)d_in[6];
    const float* cov0 = (const float*)d_in[7];
    const float* U    = (const float*)d_in[8];
    const float* dU   = (const float*)d_in[9];

    float* ws   = (float*)d_ws;
    float* CE   = ws;             // 320*128 = 40960
    float* Mrow = CE + 40960;     // 40960
    float* G    = Mrow + 40960;   // 320*64 = 20480
    float* y1   = G + 20480;      // 2560

    float* out      = (float*)d_out;
    float* out_mean = out;                      // 320*8
    float* out_c1   = out + 2560;               // 320*320*64
    float* out_cu   = out + 2560 + 320*320*64;  // 320*320

    k_phase1<<<NT, 64, 0, stream>>>(V1r, V2r, V3r, C_w, B_w, cov0, x0,
                                    CE, Mrow, G, y1);
    k_phase2<<<dim3(21, NT), 256, 0, stream>>>(Mrow, CE, y1, G, U, dU, D_w,
                                               out_c1, out_cu, out_mean);
}